// Round 3
// baseline (139.736 us; speedup 1.0000x reference)
//
#include <hip/hip_runtime.h>
#include <math.h>

#define BWALK 4096
#define NS 64
#define DD 256
#define NE 16
#define NBIN 128
#define MAXBIN 4096

typedef __attribute__((ext_vector_type(4))) float f32x4;
typedef __attribute__((ext_vector_type(8))) short s16x8;

union Frag { s16x8 v; unsigned u[4]; };

__device__ inline unsigned rne_bf16(float x) {
    unsigned u = __float_as_uint(x);
    return (u + 0x7fffu + ((u >> 16) & 1u)) >> 16;
}
__device__ inline float bf16_to_f(unsigned h) { return __uint_as_float(h << 16); }

// ---------------- kernel 1: bin (b,i) entries by slot n = R[b][i] ----------------
__global__ __launch_bounds__(256) void binbuild_kernel(
    const int* __restrict__ R, int* __restrict__ counts, int* __restrict__ binlist)
{
    const int t = blockIdx.x * 256 + threadIdx.x;   // 0..65535 = b*16+i
    const int n = R[t];
    const int pos = atomicAdd(&counts[n], 1);
    binlist[(size_t)n * MAXBIN + pos] = t;
}

// ---------------- kernel 2: binned orbital GEMM via split-bf16 MFMA ----------------
// block = (chunk, bin). M[n] staged in LDS once, held as bf16 hi/lo B-fragments in
// registers; per 16-entry tile: gather y rows -> split-bf16 A-fragments -> 3 MFMA/kc.
__global__ __launch_bounds__(256) void orbitals_binned_kernel(
    const float* __restrict__ y,
    const float* __restrict__ Mup,
    const float* __restrict__ Mdn,
    const int* __restrict__ counts,
    const int* __restrict__ binlist,
    float* __restrict__ A)
{
    const int n = blockIdx.y;
    const int cnt = counts[n];
    const int start = blockIdx.x * 256;
    if (start >= cnt) return;
    const int end = min(cnt, start + 256);

    __shared__ float sM[DD * NE];   // 16 KB, M[k*16+e]

    const int tid = threadIdx.x;
    const float* Msrc = (n < NS ? Mup : Mdn) + (size_t)(n & (NS - 1)) * (DD * NE);
    {
        const f32x4* src = (const f32x4*)Msrc;
        f32x4* dst = (f32x4*)sM;
        #pragma unroll
        for (int p = 0; p < 4; ++p) dst[p * 256 + tid] = src[p * 256 + tid];
    }
    __syncthreads();

    const int lane = tid & 63;
    const int wave = tid >> 6;
    const int e  = lane & 15;   // B col / C col / entry-row this lane loads
    const int kg = lane >> 4;   // k-group

    // B fragments: lane holds M[k = kc*32 + kg*8 + j][e], j=0..7, hi/lo split
    Frag bhi[8], blo[8];
    #pragma unroll
    for (int kc = 0; kc < 8; ++kc) {
        #pragma unroll
        for (int t = 0; t < 4; ++t) {
            const int k0 = kc * 32 + kg * 8 + 2 * t;
            const float f0 = sM[k0 * 16 + e];
            const float f1 = sM[(k0 + 1) * 16 + e];
            const unsigned h0 = rne_bf16(f0), h1 = rne_bf16(f1);
            bhi[kc].u[t] = h0 | (h1 << 16);
            const unsigned l0 = rne_bf16(f0 - bf16_to_f(h0));
            const unsigned l1 = rne_bf16(f1 - bf16_to_f(h1));
            blo[kc].u[t] = l0 | (l1 << 16);
        }
    }

    const int slot = n & (NS - 1);
    const int* blist = binlist + (size_t)n * MAXBIN;

    for (int g = start + wave * 16; g < end; g += 64) {
        const int me = g + e;
        const int code = blist[me < end ? me : (end - 1)];   // entry = b*16+i
        const int b = code >> 4;
        const float* yrow = y + ((size_t)b * NS + slot) * DD + kg * 8;

        f32x4 v[8][2];
        #pragma unroll
        for (int kc = 0; kc < 8; ++kc) {
            const f32x4* p = (const f32x4*)(yrow + kc * 32);
            v[kc][0] = p[0];
            v[kc][1] = p[1];
        }

        f32x4 acc = {0.f, 0.f, 0.f, 0.f};
        #pragma unroll
        for (int kc = 0; kc < 8; ++kc) {
            Frag ahi, alo;
            #pragma unroll
            for (int t = 0; t < 4; ++t) {
                const float f0 = v[kc][t >> 1][(t & 1) * 2];
                const float f1 = v[kc][t >> 1][(t & 1) * 2 + 1];
                const unsigned h0 = rne_bf16(f0), h1 = rne_bf16(f1);
                ahi.u[t] = h0 | (h1 << 16);
                const unsigned l0 = rne_bf16(f0 - bf16_to_f(h0));
                const unsigned l1 = rne_bf16(f1 - bf16_to_f(h1));
                alo.u[t] = l0 | (l1 << 16);
            }
            acc = __builtin_amdgcn_mfma_f32_16x16x32_bf16(ahi.v, bhi[kc].v, acc, 0, 0, 0);
            acc = __builtin_amdgcn_mfma_f32_16x16x32_bf16(ahi.v, blo[kc].v, acc, 0, 0, 0);
            acc = __builtin_amdgcn_mfma_f32_16x16x32_bf16(alo.v, bhi[kc].v, acc, 0, 0, 0);
        }

        // C layout (verified m89): col = lane&15, row = (lane>>4)*4 + r
        #pragma unroll
        for (int r = 0; r < 4; ++r) {
            const int j = kg * 4 + r;
            const int jcode = __shfl(code, j, 16);
            if (g + j < end) A[(size_t)jcode * NE + e] = acc[r];
        }
    }
}

// ---------------- kernel 3: batched 16x16 LU slogdet (4 walkers / wave) ----------------
__global__ __launch_bounds__(256) void lu_det_kernel(
    const float* __restrict__ A, float* __restrict__ out, int mode)
{
    const int tid = threadIdx.x;
    const int w = blockIdx.x * 16 + (tid >> 4);   // walker
    const int lane = tid & 15;                     // row of this walker's matrix

    float a[NE];
    {
        const f32x4* p = (const f32x4*)(A + ((size_t)w * NE + lane) * NE);
        #pragma unroll
        for (int q = 0; q < 4; ++q) {
            const f32x4 vv = p[q];
            a[q * 4 + 0] = vv[0]; a[q * 4 + 1] = vv[1];
            a[q * 4 + 2] = vv[2]; a[q * 4 + 3] = vv[3];
        }
    }

    unsigned used = 0u;
    float logabs = 0.0f;
    int neg = 0;
    int perm[NE];

    #pragma unroll
    for (int k = 0; k < NE; ++k) {
        float v = ((used >> lane) & 1u) ? -1.0f : fabsf(a[k]);
        int bi = lane;
        #pragma unroll
        for (int off = 8; off > 0; off >>= 1) {
            const float ov = __shfl_xor(v, off, 16);
            const int   oi = __shfl_xor(bi, off, 16);
            if (ov > v || (ov == v && oi < bi)) { v = ov; bi = oi; }
        }
        const int p = bi;
        perm[k] = p;
        const float pivval = __shfl(a[k], p, 16);
        const bool active = (((used >> lane) & 1u) == 0u) && (lane != p);
        const float m = active ? (a[k] / pivval) : 0.0f;
        #pragma unroll
        for (int ee = k + 1; ee < NE; ++ee) {
            const float pe = __shfl(a[ee], p, 16);
            a[ee] = fmaf(-m, pe, a[ee]);
        }
        used |= (1u << p);
        logabs += logf(fabsf(pivval));
        neg ^= (pivval < 0.0f) ? 1 : 0;
    }

    int inv = 0;
    #pragma unroll
    for (int k1 = 0; k1 < NE; ++k1) {
        #pragma unroll
        for (int k2 = k1 + 1; k2 < NE; ++k2)
            inv ^= (perm[k1] > perm[k2]) ? 1 : 0;
    }
    neg ^= inv;

    if (lane == 0) {
        float re = logabs;
        float im = neg ? 3.14159274101257324f : 0.0f;
        if (__builtin_isnan(re)) { re = -INFINITY; im = 0.0f; }
        else if (re == -INFINITY) { im = 0.0f; }
        if (mode == 0) { out[2 * w] = re; out[2 * w + 1] = im; }
        else           { out[w] = re; }
    }
}

// ---------------- fallback: round-2 fused kernel (passing, 61.5 us) ----------------
__global__ __launch_bounds__(256) void outputheaddet_kernel(
    const float* __restrict__ y,
    const float* __restrict__ Mup,
    const float* __restrict__ Mdn,
    const int* __restrict__ R,
    float* __restrict__ out,
    int mode)
{
    const int b = blockIdx.x;
    const int tid = threadIdx.x;

    __shared__ int   sR[NE];
    __shared__ float sY[NE][DD];
    __shared__ float sA[NE][NE + 1];

    if (tid < NE) sR[tid] = R[b * NE + tid];
    __syncthreads();

    {
        const int i  = tid >> 4;
        const int d0 = (tid & 15) * 16;
        const int n    = sR[i];
        const int slot = n & (NS - 1);
        const float4* yp = reinterpret_cast<const float4*>(
            y + (((size_t)b * NS + slot) * DD + d0));
        float4 v0 = yp[0], v1 = yp[1], v2 = yp[2], v3 = yp[3];
        float4* dst = reinterpret_cast<float4*>(&sY[i][d0]);
        dst[0] = v0; dst[1] = v1; dst[2] = v2; dst[3] = v3;
    }
    __syncthreads();

    {
        const int i = tid >> 4;
        const int e = tid & 15;
        const int n    = sR[i];
        const int slot = n & (NS - 1);
        const float* Mp = (n < NS ? Mup : Mdn) + (size_t)slot * (DD * NE) + e;
        float acc = 0.0f;
        #pragma unroll 8
        for (int d = 0; d < DD; ++d)
            acc = fmaf(sY[i][d], Mp[(size_t)d * NE], acc);
        sA[i][e] = acc;
    }
    __syncthreads();

    if (tid >= NE) return;

    const int lane = tid;
    float a[NE];
    #pragma unroll
    for (int e = 0; e < NE; ++e) a[e] = sA[lane][e];

    unsigned used = 0u;
    float logabs = 0.0f;
    int neg = 0;
    int perm[NE];

    #pragma unroll
    for (int k = 0; k < NE; ++k) {
        float v = ((used >> lane) & 1u) ? -1.0f : fabsf(a[k]);
        int bi = lane;
        #pragma unroll
        for (int off = 8; off > 0; off >>= 1) {
            float ov = __shfl_xor(v, off, 16);
            int   oi = __shfl_xor(bi, off, 16);
            if (ov > v || (ov == v && oi < bi)) { v = ov; bi = oi; }
        }
        const int p = bi;
        perm[k] = p;
        const float pivval = __shfl(a[k], p, 16);
        const bool active = (((used >> lane) & 1u) == 0u) && (lane != p);
        const float m = active ? (a[k] / pivval) : 0.0f;
        #pragma unroll
        for (int e = k + 1; e < NE; ++e) {
            const float pe = __shfl(a[e], p, 16);
            a[e] = fmaf(-m, pe, a[e]);
        }
        used |= (1u << p);
        logabs += logf(fabsf(pivval));
        neg ^= (pivval < 0.0f) ? 1 : 0;
    }

    int inv = 0;
    #pragma unroll
    for (int k1 = 0; k1 < NE; ++k1) {
        #pragma unroll
        for (int k2 = k1 + 1; k2 < NE; ++k2)
            inv ^= (perm[k1] > perm[k2]) ? 1 : 0;
    }
    neg ^= inv;

    if (lane == 0) {
        float re = logabs;
        float im = neg ? 3.14159274101257324f : 0.0f;
        if (__builtin_isnan(re)) { re = -INFINITY; im = 0.0f; }
        else if (re == -INFINITY) { im = 0.0f; }
        if (mode == 0) { out[2 * b] = re; out[2 * b + 1] = im; }
        else           { out[b] = re; }
    }
}

extern "C" void kernel_launch(void* const* d_in, const int* in_sizes, int n_in,
                              void* d_out, int out_size, void* d_ws, size_t ws_size,
                              hipStream_t stream) {
    const float* y   = (const float*)d_in[0];
    const float* Mup = (const float*)d_in[1];
    const float* Mdn = (const float*)d_in[2];
    const int*   R   = (const int*)d_in[3];
    float* out = (float*)d_out;

    const int mode = (out_size >= 2 * BWALK) ? 0 : 1;

    const size_t off_list = 1024;
    const size_t off_A    = off_list + (size_t)NBIN * MAXBIN * sizeof(int);
    const size_t need     = off_A + (size_t)BWALK * NE * NE * sizeof(float);

    if (ws_size >= need) {
        int*   counts  = (int*)d_ws;
        int*   binlist = (int*)((char*)d_ws + off_list);
        float* A       = (float*)((char*)d_ws + off_A);

        hipMemsetAsync(counts, 0, NBIN * sizeof(int), stream);
        hipLaunchKernelGGL(binbuild_kernel, dim3(BWALK * NE / 256), dim3(256), 0, stream,
                           R, counts, binlist);
        hipLaunchKernelGGL(orbitals_binned_kernel, dim3(16, NBIN), dim3(256), 0, stream,
                           y, Mup, Mdn, counts, binlist, A);
        hipLaunchKernelGGL(lu_det_kernel, dim3(BWALK / 16), dim3(256), 0, stream,
                           A, out, mode);
    } else {
        hipLaunchKernelGGL(outputheaddet_kernel, dim3(BWALK), dim3(256), 0, stream,
                           y, Mup, Mdn, R, out, mode);
    }
}

// Round 4
// 42.876 us; speedup vs baseline: 3.2591x; 3.2591x over previous
//
#include <hip/hip_runtime.h>
#include <math.h>

#define BWALK 4096
#define NS 64
#define DD 256
#define NE 16
#define NSLOT 128
#define CHUNK 1024   // walkers per orbitals block

typedef __attribute__((ext_vector_type(4))) float f32x4;
typedef __attribute__((ext_vector_type(8))) short s16x8;

union Frag { s16x8 v; unsigned u[4]; };

__device__ inline unsigned rne_bf16(float x) {
    unsigned u = __float_as_uint(x);
    return (u + 0x7fffu + ((u >> 16) & 1u)) >> 16;
}
__device__ inline float bf16_to_f(unsigned h) { return __uint_as_float(h << 16); }

// ---------- kernel 1: per-(slot, walker-chunk) gathered orbital GEMM ----------
// No binning pass: R has <=1 occurrence of slot n per walker (permutation), so
// each block rescans its chunk's R rows (L2-resident) and compacts matches in LDS.
__global__ __launch_bounds__(256) void orbitals_kernel(
    const float* __restrict__ y,
    const float* __restrict__ Mup,
    const float* __restrict__ Mdn,
    const int* __restrict__ R,
    float* __restrict__ A)
{
    const int n   = blockIdx.y;            // orbital slot 0..127
    const int b0  = blockIdx.x * CHUNK;    // first walker of this chunk
    const int tid = threadIdx.x;
    const int lane = tid & 63;
    const int wv   = tid >> 6;

    __shared__ float sM[DD * NE];          // 16 KB
    __shared__ int   sCode[CHUNK];         // 4 KB: compacted (b<<4)|i codes
    __shared__ int   wsum[4];

    // ---- find matches: walker b matches iff n is among R[b][0..15] ----
    int m[4];
    int cnt = 0;
    #pragma unroll
    for (int q = 0; q < 4; ++q) {
        const int b = b0 + tid * 4 + q;
        const int4* rp = (const int4*)(R + (size_t)b * NE);
        int mi = -1;
        #pragma unroll
        for (int t4 = 0; t4 < 4; ++t4) {
            const int4 r4 = rp[t4];
            if (r4.x == n) mi = t4 * 4 + 0;
            if (r4.y == n) mi = t4 * 4 + 1;
            if (r4.z == n) mi = t4 * 4 + 2;
            if (r4.w == n) mi = t4 * 4 + 3;
        }
        m[q] = mi;
        cnt += (mi >= 0) ? 1 : 0;
    }

    // wave-inclusive scan of per-thread counts, then cross-wave offsets
    int incl = cnt;
    #pragma unroll
    for (int off = 1; off < 64; off <<= 1) {
        const int x = __shfl_up(incl, off, 64);
        if (lane >= off) incl += x;
    }
    if (lane == 63) wsum[wv] = incl;
    __syncthreads();
    int base = incl - cnt;
    #pragma unroll
    for (int w = 0; w < 3; ++w) if (w < wv) base += wsum[w];
    const int total = wsum[0] + wsum[1] + wsum[2] + wsum[3];

    // write compacted codes (deterministic: ordered by thread, then walker)
    {
        int p = base;
        #pragma unroll
        for (int q = 0; q < 4; ++q) {
            if (m[q] >= 0) {
                const int b = b0 + tid * 4 + q;
                sCode[p++] = (b << 4) | m[q];
            }
        }
    }

    // stage M[n] into LDS (16 KB, coalesced float4)
    {
        const float* Msrc = (n < NS ? Mup : Mdn) + (size_t)(n & (NS - 1)) * (DD * NE);
        const f32x4* src = (const f32x4*)Msrc;
        f32x4* dst = (f32x4*)sM;
        #pragma unroll
        for (int p = 0; p < 4; ++p) dst[p * 256 + tid] = src[p * 256 + tid];
    }
    __syncthreads();

    if (total == 0) return;

    const int e  = lane & 15;   // B col / C col / entry this lane loads
    const int kg = lane >> 4;   // k-group

    // B fragments: lane holds M[k = kc*32 + kg*8 + j][e], hi/lo bf16 split
    Frag bhi[8], blo[8];
    #pragma unroll
    for (int kc = 0; kc < 8; ++kc) {
        #pragma unroll
        for (int t = 0; t < 4; ++t) {
            const int k0 = kc * 32 + kg * 8 + 2 * t;
            const float f0 = sM[k0 * 16 + e];
            const float f1 = sM[(k0 + 1) * 16 + e];
            const unsigned h0 = rne_bf16(f0), h1 = rne_bf16(f1);
            bhi[kc].u[t] = h0 | (h1 << 16);
            const unsigned l0 = rne_bf16(f0 - bf16_to_f(h0));
            const unsigned l1 = rne_bf16(f1 - bf16_to_f(h1));
            blo[kc].u[t] = l0 | (l1 << 16);
        }
    }

    const int slot = n & (NS - 1);

    for (int g = wv * 16; g < total; g += 64) {
        const int me = g + e;
        const int code = sCode[me < total ? me : (total - 1)];  // (b<<4)|i
        const int b = code >> 4;
        const float* yrow = y + ((size_t)b * NS + slot) * DD + kg * 8;

        f32x4 v[8][2];
        #pragma unroll
        for (int kc = 0; kc < 8; ++kc) {
            const f32x4* p = (const f32x4*)(yrow + kc * 32);
            v[kc][0] = p[0];
            v[kc][1] = p[1];
        }

        f32x4 acc = {0.f, 0.f, 0.f, 0.f};
        #pragma unroll
        for (int kc = 0; kc < 8; ++kc) {
            Frag ahi, alo;
            #pragma unroll
            for (int t = 0; t < 4; ++t) {
                const float f0 = v[kc][t >> 1][(t & 1) * 2];
                const float f1 = v[kc][t >> 1][(t & 1) * 2 + 1];
                const unsigned h0 = rne_bf16(f0), h1 = rne_bf16(f1);
                ahi.u[t] = h0 | (h1 << 16);
                const unsigned l0 = rne_bf16(f0 - bf16_to_f(h0));
                const unsigned l1 = rne_bf16(f1 - bf16_to_f(h1));
                alo.u[t] = l0 | (l1 << 16);
            }
            acc = __builtin_amdgcn_mfma_f32_16x16x32_bf16(ahi.v, bhi[kc].v, acc, 0, 0, 0);
            acc = __builtin_amdgcn_mfma_f32_16x16x32_bf16(ahi.v, blo[kc].v, acc, 0, 0, 0);
            acc = __builtin_amdgcn_mfma_f32_16x16x32_bf16(alo.v, bhi[kc].v, acc, 0, 0, 0);
        }

        // C layout: col = lane&15, row = (lane>>4)*4 + r
        #pragma unroll
        for (int r = 0; r < 4; ++r) {
            const int j = kg * 4 + r;
            const int jcode = __shfl(code, j, 16);
            if (g + j < total) A[(size_t)jcode * NE + e] = acc[r];
        }
    }
}

// ---------- kernel 2: batched 16x16 LU slogdet (4 walkers / wave) ----------
__global__ __launch_bounds__(256) void lu_det_kernel(
    const float* __restrict__ A, float* __restrict__ out, int mode)
{
    const int tid = threadIdx.x;
    const int w = blockIdx.x * 16 + (tid >> 4);
    const int lane = tid & 15;

    float a[NE];
    {
        const f32x4* p = (const f32x4*)(A + ((size_t)w * NE + lane) * NE);
        #pragma unroll
        for (int q = 0; q < 4; ++q) {
            const f32x4 vv = p[q];
            a[q * 4 + 0] = vv[0]; a[q * 4 + 1] = vv[1];
            a[q * 4 + 2] = vv[2]; a[q * 4 + 3] = vv[3];
        }
    }

    unsigned used = 0u;
    float logabs = 0.0f;
    int neg = 0;
    int perm[NE];

    #pragma unroll
    for (int k = 0; k < NE; ++k) {
        float v = ((used >> lane) & 1u) ? -1.0f : fabsf(a[k]);
        int bi = lane;
        #pragma unroll
        for (int off = 8; off > 0; off >>= 1) {
            const float ov = __shfl_xor(v, off, 16);
            const int   oi = __shfl_xor(bi, off, 16);
            if (ov > v || (ov == v && oi < bi)) { v = ov; bi = oi; }
        }
        const int p = bi;
        perm[k] = p;
        const float pivval = __shfl(a[k], p, 16);
        const bool active = (((used >> lane) & 1u) == 0u) && (lane != p);
        const float mlt = active ? (a[k] / pivval) : 0.0f;
        #pragma unroll
        for (int ee = k + 1; ee < NE; ++ee) {
            const float pe = __shfl(a[ee], p, 16);
            a[ee] = fmaf(-mlt, pe, a[ee]);
        }
        used |= (1u << p);
        logabs += logf(fabsf(pivval));
        neg ^= (pivval < 0.0f) ? 1 : 0;
    }

    int inv = 0;
    #pragma unroll
    for (int k1 = 0; k1 < NE; ++k1) {
        #pragma unroll
        for (int k2 = k1 + 1; k2 < NE; ++k2)
            inv ^= (perm[k1] > perm[k2]) ? 1 : 0;
    }
    neg ^= inv;

    if (lane == 0) {
        float re = logabs;
        float im = neg ? 3.14159274101257324f : 0.0f;
        if (__builtin_isnan(re)) { re = -INFINITY; im = 0.0f; }
        else if (re == -INFINITY) { im = 0.0f; }
        if (mode == 0) { out[2 * w] = re; out[2 * w + 1] = im; }
        else           { out[w] = re; }
    }
}

// ---------- fallback: round-2 fused kernel (passing, 61.5 us) ----------
__global__ __launch_bounds__(256) void outputheaddet_kernel(
    const float* __restrict__ y,
    const float* __restrict__ Mup,
    const float* __restrict__ Mdn,
    const int* __restrict__ R,
    float* __restrict__ out,
    int mode)
{
    const int b = blockIdx.x;
    const int tid = threadIdx.x;

    __shared__ int   sR[NE];
    __shared__ float sY[NE][DD];
    __shared__ float sA[NE][NE + 1];

    if (tid < NE) sR[tid] = R[b * NE + tid];
    __syncthreads();

    {
        const int i  = tid >> 4;
        const int d0 = (tid & 15) * 16;
        const int n    = sR[i];
        const int slot = n & (NS - 1);
        const float4* yp = reinterpret_cast<const float4*>(
            y + (((size_t)b * NS + slot) * DD + d0));
        float4 v0 = yp[0], v1 = yp[1], v2 = yp[2], v3 = yp[3];
        float4* dst = reinterpret_cast<float4*>(&sY[i][d0]);
        dst[0] = v0; dst[1] = v1; dst[2] = v2; dst[3] = v3;
    }
    __syncthreads();

    {
        const int i = tid >> 4;
        const int e = tid & 15;
        const int n    = sR[i];
        const int slot = n & (NS - 1);
        const float* Mp = (n < NS ? Mup : Mdn) + (size_t)slot * (DD * NE) + e;
        float acc = 0.0f;
        #pragma unroll 8
        for (int d = 0; d < DD; ++d)
            acc = fmaf(sY[i][d], Mp[(size_t)d * NE], acc);
        sA[i][e] = acc;
    }
    __syncthreads();

    if (tid >= NE) return;

    const int lane = tid;
    float a[NE];
    #pragma unroll
    for (int e = 0; e < NE; ++e) a[e] = sA[lane][e];

    unsigned used = 0u;
    float logabs = 0.0f;
    int neg = 0;
    int perm[NE];

    #pragma unroll
    for (int k = 0; k < NE; ++k) {
        float v = ((used >> lane) & 1u) ? -1.0f : fabsf(a[k]);
        int bi = lane;
        #pragma unroll
        for (int off = 8; off > 0; off >>= 1) {
            float ov = __shfl_xor(v, off, 16);
            int   oi = __shfl_xor(bi, off, 16);
            if (ov > v || (ov == v && oi < bi)) { v = ov; bi = oi; }
        }
        const int p = bi;
        perm[k] = p;
        const float pivval = __shfl(a[k], p, 16);
        const bool active = (((used >> lane) & 1u) == 0u) && (lane != p);
        const float mlt = active ? (a[k] / pivval) : 0.0f;
        #pragma unroll
        for (int e = k + 1; e < NE; ++e) {
            const float pe = __shfl(a[e], p, 16);
            a[e] = fmaf(-mlt, pe, a[e]);
        }
        used |= (1u << p);
        logabs += logf(fabsf(pivval));
        neg ^= (pivval < 0.0f) ? 1 : 0;
    }

    int inv = 0;
    #pragma unroll
    for (int k1 = 0; k1 < NE; ++k1) {
        #pragma unroll
        for (int k2 = k1 + 1; k2 < NE; ++k2)
            inv ^= (perm[k1] > perm[k2]) ? 1 : 0;
    }
    neg ^= inv;

    if (lane == 0) {
        float re = logabs;
        float im = neg ? 3.14159274101257324f : 0.0f;
        if (__builtin_isnan(re)) { re = -INFINITY; im = 0.0f; }
        else if (re == -INFINITY) { im = 0.0f; }
        if (mode == 0) { out[2 * b] = re; out[2 * b + 1] = im; }
        else           { out[b] = re; }
    }
}

extern "C" void kernel_launch(void* const* d_in, const int* in_sizes, int n_in,
                              void* d_out, int out_size, void* d_ws, size_t ws_size,
                              hipStream_t stream) {
    const float* y   = (const float*)d_in[0];
    const float* Mup = (const float*)d_in[1];
    const float* Mdn = (const float*)d_in[2];
    const int*   R   = (const int*)d_in[3];
    float* out = (float*)d_out;

    const int mode = (out_size >= 2 * BWALK) ? 0 : 1;
    const size_t needA = (size_t)BWALK * NE * NE * sizeof(float);   // 4 MB

    if (ws_size >= needA) {
        float* A = (float*)d_ws;
        hipLaunchKernelGGL(orbitals_kernel, dim3(BWALK / CHUNK, NSLOT), dim3(256), 0, stream,
                           y, Mup, Mdn, R, A);
        hipLaunchKernelGGL(lu_det_kernel, dim3(BWALK / 16), dim3(256), 0, stream,
                           A, out, mode);
    } else {
        hipLaunchKernelGGL(outputheaddet_kernel, dim3(BWALK), dim3(256), 0, stream,
                           y, Mup, Mdn, R, out, mode);
    }
}